// Round 6
// baseline (386.770 us; speedup 1.0000x reference)
//
#include <hip/hip_runtime.h>
#include <math.h>

// ---------------------------------------------------------------------------
// NFM forward, fully-fused split-fp16 MFMA kernel. R9 = R8 + lgkm-only
// barriers (T4) + cross-barrier first-load hoists.
//   Mechanism: __syncthreads() emits s_waitcnt vmcnt(0) lgkmcnt(0) before
//   s_barrier -> every chunk/phase barrier drains the global-load queue and
//   re-exposes L2/L3 latency (R8's prefetch pipeline never pipelined).
//   Replacement: raw s_barrier + manual lgkmcnt(0) (cross-wave LDS visibility
//   needs lgkm only). Global loads stay in flight across barriers; first-
//   iteration B loads of each phase are hoisted above the preceding barrier.
// Everything else identical to R8 (F-swizzled activation planes, chunk-64
// double-buffered staging, 512 thr, ROWS=64, launch_bounds(512,4)).
// Stages per 64-row block:
//   FM:  tmp = 0.5*((x@V)^2 + (x^2)@(V^2))  [split-f16 xv x3 + plain-f16 sq]
//        lin = x@w_wide + b_wide            -> LDS
//   l1:  h1 = relu(tmp@w1+b1)  [split]      -> LDS
//   l2:  h2 = relu(h1@w2+b2)   [split, N pad 85->96]
//   l3:  out = sigmoid(lin + relu(h2@w3+b3)@w_out + b_out)
// MFMA = v_mfma_f32_16x16x32_f16, verified layouts:
//   A[m=lane&15][k=(lane>>4)*8+j]; D: col=lane&15, row=(lane>>4)*4+reg.
// ---------------------------------------------------------------------------

typedef _Float16 f16;
typedef _Float16 f16x8 __attribute__((ext_vector_type(8)));
typedef float f32x4 __attribute__((ext_vector_type(4)));

#define NROWS   131072
#define ROWS    64
#define FDIM    256
#define KDIM    256
#define D1      128
#define D2      85
#define D2P     96

// activation-plane swizzle (write side; m = *16-tile + q*4 + r)
#define FSW(mm) ((((mm) & 7)) ^ ((((mm) >> 3) & 1) << 1))

// workspace byte offsets (weights only; ~1.1 MB, L2-resident)
#define OFF_VT_H   0x0UL
#define OFF_VT_L   0x20000UL
#define OFF_V2T    0x40000UL
#define OFF_W1T_H  0x60000UL
#define OFF_W1T_L  0x70000UL
#define OFF_W2T_H  0x80000UL
#define OFF_W2T_L  0x86000UL
#define OFF_W3T_H  0x8C000UL
#define OFF_W3T_L  0x8F000UL

static __device__ __forceinline__ f32x4 mfma16(f16x8 a, f16x8 b, f32x4 c) {
  return __builtin_amdgcn_mfma_f32_16x16x32_f16(a, b, c, 0, 0, 0);
}

// lgkm-only barrier: drains LDS ops (cross-wave visibility) but leaves
// global loads in flight across the barrier (the whole point of R9).
static __device__ __forceinline__ void barrier_lgkm() {
  __builtin_amdgcn_sched_barrier(0);
  asm volatile("s_waitcnt lgkmcnt(0)" ::: "memory");
  __builtin_amdgcn_s_barrier();
  asm volatile("" ::: "memory");
  __builtin_amdgcn_sched_barrier(0);
}

// ---------------------------------------------------------------------------
__global__ __launch_bounds__(256) void prep_kernel(
    const float* __restrict__ V, const float* __restrict__ w1,
    const float* __restrict__ w2, const float* __restrict__ w3,
    f16* VT_h, f16* VT_l, f16* V2T,
    f16* W1T_h, f16* W1T_l, f16* W2T_h, f16* W2T_l, f16* W3T_h, f16* W3T_l) {
  int idx0 = blockIdx.x * 256 + threadIdx.x;
  int stride = gridDim.x * 256;
  for (int idx = idx0; idx < KDIM * FDIM; idx += stride) {
    int i = idx >> 8, k = idx & 255;          // read V[i][k] coalesced
    float v = V[idx];
    f16 h = (f16)v;
    int o = k * FDIM + i;                     // VT[k][i]
    VT_h[o] = h;
    VT_l[o] = (f16)(v - (float)h);
    V2T[o] = (f16)(v * v);
  }
  for (int idx = idx0; idx < D1 * KDIM; idx += stride) {
    int k = idx >> 7, n = idx & 127;          // read w1[k][n] coalesced
    float w = w1[idx];
    f16 h = (f16)w;
    int o = n * KDIM + k;                     // W1T[n][k]
    W1T_h[o] = h;
    W1T_l[o] = (f16)(w - (float)h);
  }
  for (int idx = idx0; idx < D2P * D1; idx += stride) {
    int n = idx >> 7, k = idx & 127;          // W2T[n][k], n>=85 -> 0
    float w = (n < D2) ? w2[k * D2 + n] : 0.f;
    f16 h = (f16)w;
    W2T_h[idx] = h;
    W2T_l[idx] = (f16)(w - (float)h);
  }
  for (int idx = idx0; idx < 64 * D2P; idx += stride) {
    int n = idx / D2P, k = idx - n * D2P;     // W3T[n][k], k>=85 -> 0
    float w = (k < D2) ? w3[k * 64 + n] : 0.f;
    f16 h = (f16)w;
    W3T_h[idx] = h;
    W3T_l[idx] = (f16)(w - (float)h);
  }
}

// ---------------------------------------------------------------------------
__global__ __launch_bounds__(512, 4) void fused_kernel(
    const float* __restrict__ x, const float* __restrict__ w_wide,
    const float* __restrict__ b_wide,
    const f16* __restrict__ VT_h, const f16* __restrict__ VT_l,
    const f16* __restrict__ V2T,
    const f16* __restrict__ W1T_h, const f16* __restrict__ W1T_l,
    const float* __restrict__ b1,
    const f16* __restrict__ W2T_h, const f16* __restrict__ W2T_l,
    const float* __restrict__ b2,
    const f16* __restrict__ W3T_h, const f16* __restrict__ W3T_l,
    const float* __restrict__ b3,
    const float* __restrict__ w_out, const float* __restrict__ b_out,
    float* __restrict__ out) {
  __shared__ __align__(16) f16 smem[32768];  // 64 KB arena
  __shared__ float linS[ROWS];
  __shared__ float pfS[ROWS * 2];

  // region aliases (f16 element offsets); temporally disjoint uses
  // FM staging: buf p at smem + p*12288, planes {h,l,sq} at +0/+4096/+8192
  f16* tmpH = smem;            // [64][256] F-swizzled  (FM epi .. l1 loop)
  f16* tmpL = smem + 16384;
  f16* h1H  = smem + 16384;    // [64][128] F-swizzled  (l1 epi .. l2 loop)
  f16* h1L  = smem + 24576;
  f16* h2H  = smem;            // [64][96 in s128]      (l2 epi .. l3 loop)
  f16* h2L  = smem + 8192;

  const int tid = threadIdx.x;
  const int lane = tid & 63, wv = tid >> 6;   // wv 0..7
  const int q = lane >> 4, ln = lane & 15;
  const int row0 = blockIdx.x * ROWS;
  const int srow = tid >> 3;                  // staging: 8 thr/row
  const int u8 = (tid & 7) << 3;              // 8 f32 per thread per chunk
  const int stg = srow * 64 + (((tid & 7) ^ (srow & 7)) << 3);
  const int fr = (ln & 7) ^ (((ln >> 3) & 1) << 1);

  // ---------------- FM stage: wave wv covers n in [wv*32, wv*32+32) --------
  f32x4 accV[4][2], acc2[4][2];
#pragma unroll
  for (int i = 0; i < 4; ++i)
#pragma unroll
    for (int j = 0; j < 2; ++j) {
      accV[i][j] = (f32x4){0.f, 0.f, 0.f, 0.f};
      acc2[i][j] = (f32x4){0.f, 0.f, 0.f, 0.f};
    }
  float linp = 0.f;

  float4 aP[2][2], wP[2][2];   // per-chunk in-flight globals (parity-indexed)

#define LOADG(C, P)                                                         \
  {                                                                         \
    const float* xp = x + (size_t)(row0 + srow) * FDIM + (C) * 64 + u8;     \
    const float* wp = w_wide + (C) * 64 + u8;                               \
    aP[P][0] = *(const float4*)(xp);                                        \
    aP[P][1] = *(const float4*)(xp + 4);                                    \
    wP[P][0] = *(const float4*)(wp);                                        \
    wP[P][1] = *(const float4*)(wp + 4);                                    \
  }

#define STAGE(P)                                                            \
  {                                                                         \
    f16* bb = smem + (P) * 12288;                                           \
    float v[8] = {aP[P][0].x, aP[P][0].y, aP[P][0].z, aP[P][0].w,           \
                  aP[P][1].x, aP[P][1].y, aP[P][1].z, aP[P][1].w};          \
    float w[8] = {wP[P][0].x, wP[P][0].y, wP[P][0].z, wP[P][0].w,           \
                  wP[P][1].x, wP[P][1].y, wP[P][1].z, wP[P][1].w};          \
    f16x8 hh, ll, ss;                                                       \
    _Pragma("unroll") for (int j = 0; j < 8; ++j) {                         \
      linp += v[j] * w[j];                                                  \
      f16 h = (f16)v[j];                                                    \
      hh[j] = h;                                                            \
      ll[j] = (f16)(v[j] - (float)h);                                       \
      ss[j] = (f16)(v[j] * v[j]);                                           \
    }                                                                       \
    *(f16x8*)(bb + stg) = hh;                                               \
    *(f16x8*)(bb + 4096 + stg) = ll;                                        \
    *(f16x8*)(bb + 8192 + stg) = ss;                                        \
  }

  // prologue: stage chunk 0, issue chunk 1, hoist chunk0/ksl0 B loads
  LOADG(0, 0);
  STAGE(0);
  LOADG(1, 1);
  f16x8 Bh0[2], Bl0[2], B20[2];
#pragma unroll
  for (int ni = 0; ni < 2; ++ni) {
    size_t boff = (size_t)(wv * 32 + ni * 16 + ln) * FDIM + q * 8;
    Bh0[ni] = *(const f16x8*)(VT_h + boff);
    Bl0[ni] = *(const f16x8*)(VT_l + boff);
    B20[ni] = *(const f16x8*)(V2T + boff);
  }
  barrier_lgkm();

#pragma unroll
  for (int c = 0; c < 4; ++c) {
    if (c < 2) LOADG(c + 2, c & 1);       // into the freed parity slot
    if (c < 3) STAGE((c + 1) & 1);        // overlaps MFMA(c) below
    f16* sb = smem + (c & 1) * 12288;
#pragma unroll
    for (int ksl = 0; ksl < 2; ++ksl) {
      const int k0 = c * 64 + ksl * 32;
      f16x8 Bh[2], Bl[2], B2[2];
      if (c == 0 && ksl == 0) {
#pragma unroll
        for (int ni = 0; ni < 2; ++ni) {
          Bh[ni] = Bh0[ni];
          Bl[ni] = Bl0[ni];
          B2[ni] = B20[ni];
        }
      } else {
#pragma unroll
        for (int ni = 0; ni < 2; ++ni) {
          size_t boff = (size_t)(wv * 32 + ni * 16 + ln) * FDIM + k0 + q * 8;
          Bh[ni] = *(const f16x8*)(VT_h + boff);
          Bl[ni] = *(const f16x8*)(VT_l + boff);
          B2[ni] = *(const f16x8*)(V2T + boff);
        }
      }
#pragma unroll
      for (int mi = 0; mi < 4; ++mi) {
        int aoff = (mi * 16 + ln) * 64 + ((((ksl << 2) + q) ^ (ln & 7)) << 3);
        f16x8 Ah = *(const f16x8*)(sb + aoff);
        f16x8 Al = *(const f16x8*)(sb + 4096 + aoff);
        f16x8 A2 = *(const f16x8*)(sb + 8192 + aoff);
#pragma unroll
        for (int ni = 0; ni < 2; ++ni) {
          accV[mi][ni] = mfma16(Al, Bh[ni], accV[mi][ni]);
          accV[mi][ni] = mfma16(Ah, Bl[ni], accV[mi][ni]);
          accV[mi][ni] = mfma16(Ah, Bh[ni], accV[mi][ni]);
          acc2[mi][ni] = mfma16(A2, B2[ni], acc2[mi][ni]);
        }
      }
    }
    barrier_lgkm();  // buf (c+1)&1 stores visible; buf c&1 reads done
  }
#undef LOADG
#undef STAGE

  // wide/linear part -> LDS
  {
    float s0 = linp;
    s0 += __shfl_xor(s0, 1);
    s0 += __shfl_xor(s0, 2);
    s0 += __shfl_xor(s0, 4);
    if ((tid & 7) == 0) linS[srow] = s0 + b_wide[0];
  }

  // FM epilogue: tmp = 0.5*(xv^2 + x2v2) -> LDS hi/lo, F-swizzled [m][256]
#pragma unroll
  for (int mi = 0; mi < 4; ++mi)
#pragma unroll
    for (int r = 0; r < 4; ++r) {
      int m = mi * 16 + q * 4 + r;
      int mrow = m * 256, fw = FSW(q * 4 + r);
#pragma unroll
      for (int ni = 0; ni < 2; ++ni) {
        int n = wv * 32 + ni * 16 + ln;
        float xv = accV[mi][ni][r];
        float val = 0.5f * (xv * xv + acc2[mi][ni][r]);
        f16 hi = (f16)val;
        f16 lo = (f16)(val - (float)hi);
        int off = mrow + (((n >> 3) ^ fw) << 3) + (n & 7);
        tmpH[off] = hi;
        tmpL[off] = lo;
      }
    }

  // hoist l1 ks=0 weight loads across the barrier
  const size_t w1base = (size_t)(wv * 16 + ln) * KDIM + q * 8;
  f16x8 W1h0 = *(const f16x8*)(W1T_h + w1base);
  f16x8 W1l0 = *(const f16x8*)(W1T_l + w1base);
  barrier_lgkm();

  // ---------------- l1: h1 = relu(tmp@w1+b1), N=128, K=256 -----------------
  f32x4 acc1[4];
#pragma unroll
  for (int i = 0; i < 4; ++i) acc1[i] = (f32x4){0.f, 0.f, 0.f, 0.f};

#pragma unroll
  for (int ks = 0; ks < 8; ++ks) {
    f16x8 Bh = (ks == 0) ? W1h0 : *(const f16x8*)(W1T_h + w1base + ks * 32);
    f16x8 Bl = (ks == 0) ? W1l0 : *(const f16x8*)(W1T_l + w1base + ks * 32);
#pragma unroll
    for (int mi = 0; mi < 4; ++mi) {
      int m = mi * 16 + ln;
      int aoff = m * 256 + (((ks * 4 + q) ^ fr) << 3);
      f16x8 Ah = *(const f16x8*)(tmpH + aoff);
      f16x8 Al = *(const f16x8*)(tmpL + aoff);
      acc1[mi] = mfma16(Al, Bh, acc1[mi]);
      acc1[mi] = mfma16(Ah, Bl, acc1[mi]);
      acc1[mi] = mfma16(Ah, Bh, acc1[mi]);
    }
  }

  barrier_lgkm();  // tmp reads done; upper half may be overwritten

  // l1 epilogue -> h1 planes (upper half), F-swizzled [m][128]
  {
    int n = wv * 16 + ln;
    float bias = b1[n];
#pragma unroll
    for (int mi = 0; mi < 4; ++mi)
#pragma unroll
      for (int r = 0; r < 4; ++r) {
        int m = mi * 16 + q * 4 + r;
        float z = acc1[mi][r] + bias;
        z = z > 0.f ? z : 0.f;
        f16 hi = (f16)z;
        f16 lo = (f16)(z - (float)hi);
        int off = m * 128 + (((n >> 3) ^ FSW(q * 4 + r)) << 3) + (n & 7);
        h1H[off] = hi;
        h1L[off] = lo;
      }
  }

  // hoist l2 ks=0 weight loads across the barrier
  const int mt = wv & 3, half = wv >> 2;
  f16x8 W2h0[3], W2l0[3];
#pragma unroll
  for (int nj = 0; nj < 3; ++nj) {
    size_t boff = (size_t)((half * 3 + nj) * 16 + ln) * D1 + q * 8;
    W2h0[nj] = *(const f16x8*)(W2T_h + boff);
    W2l0[nj] = *(const f16x8*)(W2T_l + boff);
  }
  barrier_lgkm();

  // ---------------- l2: h2 = relu(h1@w2+b2), N=96(pad), K=128 --------------
  f32x4 accL2[3];
#pragma unroll
  for (int j = 0; j < 3; ++j) accL2[j] = (f32x4){0.f, 0.f, 0.f, 0.f};

#pragma unroll
  for (int ks = 0; ks < 4; ++ks) {
    int m = mt * 16 + ln;
    int aoff = m * 128 + (((ks * 4 + q) ^ fr) << 3);
    f16x8 Ah = *(const f16x8*)(h1H + aoff);
    f16x8 Al = *(const f16x8*)(h1L + aoff);
#pragma unroll
    for (int nj = 0; nj < 3; ++nj) {
      size_t boff =
          (size_t)((half * 3 + nj) * 16 + ln) * D1 + ks * 32 + q * 8;
      f16x8 Bh = (ks == 0) ? W2h0[nj] : *(const f16x8*)(W2T_h + boff);
      f16x8 Bl = (ks == 0) ? W2l0[nj] : *(const f16x8*)(W2T_l + boff);
      accL2[nj] = mfma16(Al, Bh, accL2[nj]);
      accL2[nj] = mfma16(Ah, Bl, accL2[nj]);
      accL2[nj] = mfma16(Ah, Bh, accL2[nj]);
    }
  }

  // l2 epilogue -> h2 planes (region disjoint from h1): no barrier before
#pragma unroll
  for (int r = 0; r < 4; ++r) {
    int m = mt * 16 + q * 4 + r;
    int mrow = m * 128, fw = FSW(q * 4 + r);
#pragma unroll
    for (int nj = 0; nj < 3; ++nj) {
      int n = (half * 3 + nj) * 16 + ln;
      float z = accL2[nj][r] + ((n < D2) ? b2[n] : 0.f);
      z = z > 0.f ? z : 0.f;
      f16 hi = (f16)z;
      f16 lo = (f16)(z - (float)hi);
      int off = mrow + (((n >> 3) ^ fw) << 3) + (n & 7);
      h2H[off] = hi;
      h2L[off] = lo;
    }
  }

  // hoist l3 ks=0 weight loads across the barrier
  f16x8 W3h0[2], W3l0[2];
#pragma unroll
  for (int nj = 0; nj < 2; ++nj) {
    size_t boff = (size_t)((half * 2 + nj) * 16 + ln) * D2P + q * 8;
    W3h0[nj] = *(const f16x8*)(W3T_h + boff);
    W3l0[nj] = *(const f16x8*)(W3T_l + boff);
  }
  barrier_lgkm();

  // ---------------- l3 + out: K=96, N=64 ----------------
  f32x4 accL3[2];
  accL3[0] = (f32x4){0.f, 0.f, 0.f, 0.f};
  accL3[1] = (f32x4){0.f, 0.f, 0.f, 0.f};

#pragma unroll
  for (int ks = 0; ks < 3; ++ks) {
    int m = mt * 16 + ln;
    int aoff = m * 128 + (((ks * 4 + q) ^ fr) << 3);
    f16x8 Ah = *(const f16x8*)(h2H + aoff);
    f16x8 Al = *(const f16x8*)(h2L + aoff);
#pragma unroll
    for (int nj = 0; nj < 2; ++nj) {
      size_t boff =
          (size_t)((half * 2 + nj) * 16 + ln) * D2P + ks * 32 + q * 8;
      f16x8 Bh = (ks == 0) ? W3h0[nj] : *(const f16x8*)(W3T_h + boff);
      f16x8 Bl = (ks == 0) ? W3l0[nj] : *(const f16x8*)(W3T_l + boff);
      accL3[nj] = mfma16(Al, Bh, accL3[nj]);
      accL3[nj] = mfma16(Ah, Bl, accL3[nj]);
      accL3[nj] = mfma16(Ah, Bh, accL3[nj]);
    }
  }

  {
    float b3v[2], wov[2];
#pragma unroll
    for (int nj = 0; nj < 2; ++nj) {
      int n = (half * 2 + nj) * 16 + ln;
      b3v[nj] = b3[n];
      wov[nj] = w_out[n];
    }
#pragma unroll
    for (int r = 0; r < 4; ++r) {
      float part = 0.f;
#pragma unroll
      for (int nj = 0; nj < 2; ++nj) {
        float z = accL3[nj][r] + b3v[nj];
        part += (z > 0.f ? z : 0.f) * wov[nj];
      }
      part += __shfl_xor(part, 1);
      part += __shfl_xor(part, 2);
      part += __shfl_xor(part, 4);
      part += __shfl_xor(part, 8);
      if (ln == 0) pfS[(mt * 16 + q * 4 + r) * 2 + half] = part;
    }
  }

  __syncthreads();

  if (tid < ROWS) {
    float zf = linS[tid] + pfS[tid * 2] + pfS[tid * 2 + 1] + b_out[0];
    out[row0 + tid] = 1.f / (1.f + expf(-zf));
  }
}

// ---------------------------------------------------------------------------
extern "C" void kernel_launch(void* const* d_in, const int* in_sizes, int n_in,
                              void* d_out, int out_size, void* d_ws, size_t ws_size,
                              hipStream_t stream) {
  const float* x = (const float*)d_in[0];
  const float* w_wide = (const float*)d_in[1];
  const float* b_wide = (const float*)d_in[2];
  const float* V = (const float*)d_in[3];
  const float* w1 = (const float*)d_in[4];
  const float* b1 = (const float*)d_in[5];
  const float* w2 = (const float*)d_in[6];
  const float* b2 = (const float*)d_in[7];
  const float* w3 = (const float*)d_in[8];
  const float* b3 = (const float*)d_in[9];
  const float* w_out = (const float*)d_in[10];
  const float* b_out = (const float*)d_in[11];
  float* out = (float*)d_out;
  char* ws = (char*)d_ws;

  f16* VT_h = (f16*)(ws + OFF_VT_H);
  f16* VT_l = (f16*)(ws + OFF_VT_L);
  f16* V2T = (f16*)(ws + OFF_V2T);
  f16* W1T_h = (f16*)(ws + OFF_W1T_H);
  f16* W1T_l = (f16*)(ws + OFF_W1T_L);
  f16* W2T_h = (f16*)(ws + OFF_W2T_H);
  f16* W2T_l = (f16*)(ws + OFF_W2T_L);
  f16* W3T_h = (f16*)(ws + OFF_W3T_H);
  f16* W3T_l = (f16*)(ws + OFF_W3T_L);

  prep_kernel<<<256, 256, 0, stream>>>(V, w1, w2, w3, VT_h, VT_l, V2T, W1T_h,
                                       W1T_l, W2T_h, W2T_l, W3T_h, W3T_l);

  fused_kernel<<<NROWS / ROWS, 512, 0, stream>>>(
      x, w_wide, b_wide, VT_h, VT_l, V2T, W1T_h, W1T_l, b1, W2T_h, W2T_l, b2,
      W3T_h, W3T_l, b3, w_out, b_out, out);
}

// Round 7
// 376.777 us; speedup vs baseline: 1.0265x; 1.0265x over previous
//
#include <hip/hip_runtime.h>
#include <math.h>

// ---------------------------------------------------------------------------
// NFM forward, fully-fused split-fp16 MFMA kernel. R10 = R8 + lgkm-only
// barriers, NO hoists (unbundles R9's two changes; R9's cross-barrier weight
// hoists spilled — WRITE_SIZE 23.6->61.9 MB — masking the barrier effect).
//   barrier_lgkm: raw s_barrier + s_waitcnt lgkmcnt(0) only. Cross-wave LDS
//   visibility needs lgkm only; global loads (the LOADG x-prefetch chain and
//   compiler-scheduled first B-loads of each chunk) stay in flight across
//   barriers instead of being drained by __syncthreads' vmcnt(0).
//   Zero register cost vs R8.
// Everything else identical to R8:
//   - F-swizzle on activation planes: F(m) = (m&7) ^ (((m>>3)&1)<<1).
//   - FM staging: double-buffered chunk=64 pipeline (2 x 3 x 8KB = 48KB),
//     one barrier per chunk; convert+store(c+1) overlaps MFMA(c).
//   - 512 thr, ROWS=64, 2 blocks/CU, launch_bounds(512,4), no setprio.
// Stages per 64-row block:
//   FM:  tmp = 0.5*((x@V)^2 + (x^2)@(V^2))  [split-f16 xv x3 + plain-f16 sq]
//        lin = x@w_wide + b_wide            -> LDS
//   l1:  h1 = relu(tmp@w1+b1)  [split]      -> LDS
//   l2:  h2 = relu(h1@w2+b2)   [split, N pad 85->96]
//   l3:  out = sigmoid(lin + relu(h2@w3+b3)@w_out + b_out)
// MFMA = v_mfma_f32_16x16x32_f16, verified layouts:
//   A[m=lane&15][k=(lane>>4)*8+j]; D: col=lane&15, row=(lane>>4)*4+reg.
// ---------------------------------------------------------------------------

typedef _Float16 f16;
typedef _Float16 f16x8 __attribute__((ext_vector_type(8)));
typedef float f32x4 __attribute__((ext_vector_type(4)));

#define NROWS   131072
#define ROWS    64
#define FDIM    256
#define KDIM    256
#define D1      128
#define D2      85
#define D2P     96

// activation-plane swizzle (write side; m = *16-tile + q*4 + r)
#define FSW(mm) ((((mm) & 7)) ^ ((((mm) >> 3) & 1) << 1))

// workspace byte offsets (weights only; ~1.1 MB, L2-resident)
#define OFF_VT_H   0x0UL
#define OFF_VT_L   0x20000UL
#define OFF_V2T    0x40000UL
#define OFF_W1T_H  0x60000UL
#define OFF_W1T_L  0x70000UL
#define OFF_W2T_H  0x80000UL
#define OFF_W2T_L  0x86000UL
#define OFF_W3T_H  0x8C000UL
#define OFF_W3T_L  0x8F000UL

static __device__ __forceinline__ f32x4 mfma16(f16x8 a, f16x8 b, f32x4 c) {
  return __builtin_amdgcn_mfma_f32_16x16x32_f16(a, b, c, 0, 0, 0);
}

// lgkm-only barrier: drains LDS ops (cross-wave visibility) but leaves
// global loads in flight across the barrier. sched_barrier(0) fences per
// guide rule #18 (compiler may hoist register-only MFMA past inline-asm
// waitcnt otherwise).
static __device__ __forceinline__ void barrier_lgkm() {
  __builtin_amdgcn_sched_barrier(0);
  asm volatile("s_waitcnt lgkmcnt(0)" ::: "memory");
  __builtin_amdgcn_s_barrier();
  asm volatile("" ::: "memory");
  __builtin_amdgcn_sched_barrier(0);
}

// ---------------------------------------------------------------------------
__global__ __launch_bounds__(256) void prep_kernel(
    const float* __restrict__ V, const float* __restrict__ w1,
    const float* __restrict__ w2, const float* __restrict__ w3,
    f16* VT_h, f16* VT_l, f16* V2T,
    f16* W1T_h, f16* W1T_l, f16* W2T_h, f16* W2T_l, f16* W3T_h, f16* W3T_l) {
  int idx0 = blockIdx.x * 256 + threadIdx.x;
  int stride = gridDim.x * 256;
  for (int idx = idx0; idx < KDIM * FDIM; idx += stride) {
    int i = idx >> 8, k = idx & 255;          // read V[i][k] coalesced
    float v = V[idx];
    f16 h = (f16)v;
    int o = k * FDIM + i;                     // VT[k][i]
    VT_h[o] = h;
    VT_l[o] = (f16)(v - (float)h);
    V2T[o] = (f16)(v * v);
  }
  for (int idx = idx0; idx < D1 * KDIM; idx += stride) {
    int k = idx >> 7, n = idx & 127;          // read w1[k][n] coalesced
    float w = w1[idx];
    f16 h = (f16)w;
    int o = n * KDIM + k;                     // W1T[n][k]
    W1T_h[o] = h;
    W1T_l[o] = (f16)(w - (float)h);
  }
  for (int idx = idx0; idx < D2P * D1; idx += stride) {
    int n = idx >> 7, k = idx & 127;          // W2T[n][k], n>=85 -> 0
    float w = (n < D2) ? w2[k * D2 + n] : 0.f;
    f16 h = (f16)w;
    W2T_h[idx] = h;
    W2T_l[idx] = (f16)(w - (float)h);
  }
  for (int idx = idx0; idx < 64 * D2P; idx += stride) {
    int n = idx / D2P, k = idx - n * D2P;     // W3T[n][k], k>=85 -> 0
    float w = (k < D2) ? w3[k * 64 + n] : 0.f;
    f16 h = (f16)w;
    W3T_h[idx] = h;
    W3T_l[idx] = (f16)(w - (float)h);
  }
}

// ---------------------------------------------------------------------------
__global__ __launch_bounds__(512, 4) void fused_kernel(
    const float* __restrict__ x, const float* __restrict__ w_wide,
    const float* __restrict__ b_wide,
    const f16* __restrict__ VT_h, const f16* __restrict__ VT_l,
    const f16* __restrict__ V2T,
    const f16* __restrict__ W1T_h, const f16* __restrict__ W1T_l,
    const float* __restrict__ b1,
    const f16* __restrict__ W2T_h, const f16* __restrict__ W2T_l,
    const float* __restrict__ b2,
    const f16* __restrict__ W3T_h, const f16* __restrict__ W3T_l,
    const float* __restrict__ b3,
    const float* __restrict__ w_out, const float* __restrict__ b_out,
    float* __restrict__ out) {
  __shared__ __align__(16) f16 smem[32768];  // 64 KB arena
  __shared__ float linS[ROWS];
  __shared__ float pfS[ROWS * 2];

  // region aliases (f16 element offsets); temporally disjoint uses
  // FM staging: buf p at smem + p*12288, planes {h,l,sq} at +0/+4096/+8192
  f16* tmpH = smem;            // [64][256] F-swizzled  (FM epi .. l1 loop)
  f16* tmpL = smem + 16384;
  f16* h1H  = smem + 16384;    // [64][128] F-swizzled  (l1 epi .. l2 loop)
  f16* h1L  = smem + 24576;
  f16* h2H  = smem;            // [64][96 in s128]      (l2 epi .. l3 loop)
  f16* h2L  = smem + 8192;

  const int tid = threadIdx.x;
  const int lane = tid & 63, wv = tid >> 6;   // wv 0..7
  const int q = lane >> 4, ln = lane & 15;
  const int row0 = blockIdx.x * ROWS;
  const int srow = tid >> 3;                  // staging: 8 thr/row
  const int u8 = (tid & 7) << 3;              // 8 f32 per thread per chunk
  const int stg = srow * 64 + (((tid & 7) ^ (srow & 7)) << 3);
  const int fr = (ln & 7) ^ (((ln >> 3) & 1) << 1);

  // ---------------- FM stage: wave wv covers n in [wv*32, wv*32+32) --------
  f32x4 accV[4][2], acc2[4][2];
#pragma unroll
  for (int i = 0; i < 4; ++i)
#pragma unroll
    for (int j = 0; j < 2; ++j) {
      accV[i][j] = (f32x4){0.f, 0.f, 0.f, 0.f};
      acc2[i][j] = (f32x4){0.f, 0.f, 0.f, 0.f};
    }
  float linp = 0.f;

  float4 aP[2][2], wP[2][2];   // per-chunk in-flight globals (parity-indexed)

#define LOADG(C, P)                                                         \
  {                                                                         \
    const float* xp = x + (size_t)(row0 + srow) * FDIM + (C) * 64 + u8;     \
    const float* wp = w_wide + (C) * 64 + u8;                               \
    aP[P][0] = *(const float4*)(xp);                                        \
    aP[P][1] = *(const float4*)(xp + 4);                                    \
    wP[P][0] = *(const float4*)(wp);                                        \
    wP[P][1] = *(const float4*)(wp + 4);                                    \
  }

#define STAGE(P)                                                            \
  {                                                                         \
    f16* bb = smem + (P) * 12288;                                           \
    float v[8] = {aP[P][0].x, aP[P][0].y, aP[P][0].z, aP[P][0].w,           \
                  aP[P][1].x, aP[P][1].y, aP[P][1].z, aP[P][1].w};          \
    float w[8] = {wP[P][0].x, wP[P][0].y, wP[P][0].z, wP[P][0].w,           \
                  wP[P][1].x, wP[P][1].y, wP[P][1].z, wP[P][1].w};          \
    f16x8 hh, ll, ss;                                                       \
    _Pragma("unroll") for (int j = 0; j < 8; ++j) {                         \
      linp += v[j] * w[j];                                                  \
      f16 h = (f16)v[j];                                                    \
      hh[j] = h;                                                            \
      ll[j] = (f16)(v[j] - (float)h);                                       \
      ss[j] = (f16)(v[j] * v[j]);                                           \
    }                                                                       \
    *(f16x8*)(bb + stg) = hh;                                               \
    *(f16x8*)(bb + 4096 + stg) = ll;                                        \
    *(f16x8*)(bb + 8192 + stg) = ss;                                        \
  }

  // prologue: stage chunk 0, issue chunk 1
  LOADG(0, 0);
  STAGE(0);
  LOADG(1, 1);
  barrier_lgkm();

#pragma unroll
  for (int c = 0; c < 4; ++c) {
    if (c < 2) LOADG(c + 2, c & 1);       // into the freed parity slot
    if (c < 3) STAGE((c + 1) & 1);        // overlaps MFMA(c) below
    f16* sb = smem + (c & 1) * 12288;
#pragma unroll
    for (int ksl = 0; ksl < 2; ++ksl) {
      const int k0 = c * 64 + ksl * 32;
      f16x8 Bh[2], Bl[2], B2[2];
#pragma unroll
      for (int ni = 0; ni < 2; ++ni) {
        int n = wv * 32 + ni * 16 + ln;
        size_t boff = (size_t)n * FDIM + k0 + q * 8;
        Bh[ni] = *(const f16x8*)(VT_h + boff);
        Bl[ni] = *(const f16x8*)(VT_l + boff);
        B2[ni] = *(const f16x8*)(V2T + boff);
      }
#pragma unroll
      for (int mi = 0; mi < 4; ++mi) {
        int aoff = (mi * 16 + ln) * 64 + ((((ksl << 2) + q) ^ (ln & 7)) << 3);
        f16x8 Ah = *(const f16x8*)(sb + aoff);
        f16x8 Al = *(const f16x8*)(sb + 4096 + aoff);
        f16x8 A2 = *(const f16x8*)(sb + 8192 + aoff);
#pragma unroll
        for (int ni = 0; ni < 2; ++ni) {
          accV[mi][ni] = mfma16(Al, Bh[ni], accV[mi][ni]);
          accV[mi][ni] = mfma16(Ah, Bl[ni], accV[mi][ni]);
          accV[mi][ni] = mfma16(Ah, Bh[ni], accV[mi][ni]);
          acc2[mi][ni] = mfma16(A2, B2[ni], acc2[mi][ni]);
        }
      }
    }
    barrier_lgkm();  // buf (c+1)&1 stores visible; buf c&1 reads done
  }
#undef LOADG
#undef STAGE

  // wide/linear part -> LDS
  {
    float s0 = linp;
    s0 += __shfl_xor(s0, 1);
    s0 += __shfl_xor(s0, 2);
    s0 += __shfl_xor(s0, 4);
    if ((tid & 7) == 0) linS[srow] = s0 + b_wide[0];
  }

  // FM epilogue: tmp = 0.5*(xv^2 + x2v2) -> LDS hi/lo, F-swizzled [m][256]
#pragma unroll
  for (int mi = 0; mi < 4; ++mi)
#pragma unroll
    for (int r = 0; r < 4; ++r) {
      int m = mi * 16 + q * 4 + r;
      int mrow = m * 256, fw = FSW(q * 4 + r);
#pragma unroll
      for (int ni = 0; ni < 2; ++ni) {
        int n = wv * 32 + ni * 16 + ln;
        float xv = accV[mi][ni][r];
        float val = 0.5f * (xv * xv + acc2[mi][ni][r]);
        f16 hi = (f16)val;
        f16 lo = (f16)(val - (float)hi);
        int off = mrow + (((n >> 3) ^ fw) << 3) + (n & 7);
        tmpH[off] = hi;
        tmpL[off] = lo;
      }
    }

  barrier_lgkm();

  // ---------------- l1: h1 = relu(tmp@w1+b1), N=128, K=256 -----------------
  // wave wv handles n-tile wv (n = wv*16+ln), all 4 m-tiles
  f32x4 acc1[4];
#pragma unroll
  for (int i = 0; i < 4; ++i) acc1[i] = (f32x4){0.f, 0.f, 0.f, 0.f};

#pragma unroll
  for (int ks = 0; ks < 8; ++ks) {
    size_t boff = (size_t)(wv * 16 + ln) * KDIM + ks * 32 + q * 8;
    f16x8 Bh = *(const f16x8*)(W1T_h + boff);
    f16x8 Bl = *(const f16x8*)(W1T_l + boff);
#pragma unroll
    for (int mi = 0; mi < 4; ++mi) {
      int m = mi * 16 + ln;
      int aoff = m * 256 + (((ks * 4 + q) ^ fr) << 3);
      f16x8 Ah = *(const f16x8*)(tmpH + aoff);
      f16x8 Al = *(const f16x8*)(tmpL + aoff);
      acc1[mi] = mfma16(Al, Bh, acc1[mi]);
      acc1[mi] = mfma16(Ah, Bl, acc1[mi]);
      acc1[mi] = mfma16(Ah, Bh, acc1[mi]);
    }
  }

  barrier_lgkm();  // tmp reads done; upper half may be overwritten

  // l1 epilogue -> h1 planes (upper half), F-swizzled [m][128]
  {
    int n = wv * 16 + ln;
    float bias = b1[n];
#pragma unroll
    for (int mi = 0; mi < 4; ++mi)
#pragma unroll
      for (int r = 0; r < 4; ++r) {
        int m = mi * 16 + q * 4 + r;
        float z = acc1[mi][r] + bias;
        z = z > 0.f ? z : 0.f;
        f16 hi = (f16)z;
        f16 lo = (f16)(z - (float)hi);
        int off = m * 128 + (((n >> 3) ^ FSW(q * 4 + r)) << 3) + (n & 7);
        h1H[off] = hi;
        h1L[off] = lo;
      }
  }

  barrier_lgkm();

  // ---------------- l2: h2 = relu(h1@w2+b2), N=96(pad), K=128 --------------
  // wave (mt = wv&3, half = wv>>2): rows mt*16..+15, n-tiles half*3..half*3+2
  const int mt = wv & 3, half = wv >> 2;
  f32x4 accL2[3];
#pragma unroll
  for (int j = 0; j < 3; ++j) accL2[j] = (f32x4){0.f, 0.f, 0.f, 0.f};

#pragma unroll
  for (int ks = 0; ks < 4; ++ks) {
    int m = mt * 16 + ln;
    int aoff = m * 128 + (((ks * 4 + q) ^ fr) << 3);
    f16x8 Ah = *(const f16x8*)(h1H + aoff);
    f16x8 Al = *(const f16x8*)(h1L + aoff);
#pragma unroll
    for (int nj = 0; nj < 3; ++nj) {
      int n = (half * 3 + nj) * 16 + ln;
      size_t boff = (size_t)n * D1 + ks * 32 + q * 8;
      f16x8 Bh = *(const f16x8*)(W2T_h + boff);
      f16x8 Bl = *(const f16x8*)(W2T_l + boff);
      accL2[nj] = mfma16(Al, Bh, accL2[nj]);
      accL2[nj] = mfma16(Ah, Bl, accL2[nj]);
      accL2[nj] = mfma16(Ah, Bh, accL2[nj]);
    }
  }

  // l2 epilogue -> h2 planes (lower region, disjoint from h1): no barrier
#pragma unroll
  for (int r = 0; r < 4; ++r) {
    int m = mt * 16 + q * 4 + r;
    int mrow = m * 128, fw = FSW(q * 4 + r);
#pragma unroll
    for (int nj = 0; nj < 3; ++nj) {
      int n = (half * 3 + nj) * 16 + ln;
      float z = accL2[nj][r] + ((n < D2) ? b2[n] : 0.f);
      z = z > 0.f ? z : 0.f;
      f16 hi = (f16)z;
      f16 lo = (f16)(z - (float)hi);
      int off = mrow + (((n >> 3) ^ fw) << 3) + (n & 7);
      h2H[off] = hi;
      h2L[off] = lo;
    }
  }

  barrier_lgkm();

  // ---------------- l3 + out: K=96, N=64 ----------------
  // wave (mt, half): rows mt*16..+15, n-tiles half*2, half*2+1
  f32x4 accL3[2];
  accL3[0] = (f32x4){0.f, 0.f, 0.f, 0.f};
  accL3[1] = (f32x4){0.f, 0.f, 0.f, 0.f};

#pragma unroll
  for (int ks = 0; ks < 3; ++ks) {
    int m = mt * 16 + ln;
    int aoff = m * 128 + (((ks * 4 + q) ^ fr) << 3);
    f16x8 Ah = *(const f16x8*)(h2H + aoff);
    f16x8 Al = *(const f16x8*)(h2L + aoff);
#pragma unroll
    for (int nj = 0; nj < 2; ++nj) {
      int n = (half * 2 + nj) * 16 + ln;
      size_t boff = (size_t)n * D2P + ks * 32 + q * 8;
      f16x8 Bh = *(const f16x8*)(W3T_h + boff);
      f16x8 Bl = *(const f16x8*)(W3T_l + boff);
      accL3[nj] = mfma16(Al, Bh, accL3[nj]);
      accL3[nj] = mfma16(Ah, Bl, accL3[nj]);
      accL3[nj] = mfma16(Ah, Bh, accL3[nj]);
    }
  }

  {
    float b3v[2], wov[2];
#pragma unroll
    for (int nj = 0; nj < 2; ++nj) {
      int n = (half * 2 + nj) * 16 + ln;
      b3v[nj] = b3[n];
      wov[nj] = w_out[n];
    }
#pragma unroll
    for (int r = 0; r < 4; ++r) {
      float part = 0.f;
#pragma unroll
      for (int nj = 0; nj < 2; ++nj) {
        float z = accL3[nj][r] + b3v[nj];
        part += (z > 0.f ? z : 0.f) * wov[nj];
      }
      part += __shfl_xor(part, 1);
      part += __shfl_xor(part, 2);
      part += __shfl_xor(part, 4);
      part += __shfl_xor(part, 8);
      if (ln == 0) pfS[(mt * 16 + q * 4 + r) * 2 + half] = part;
    }
  }

  __syncthreads();

  if (tid < ROWS) {
    float zf = linS[tid] + pfS[tid * 2] + pfS[tid * 2 + 1] + b_out[0];
    out[row0 + tid] = 1.f / (1.f + expf(-zf));
  }
}

// ---------------------------------------------------------------------------
extern "C" void kernel_launch(void* const* d_in, const int* in_sizes, int n_in,
                              void* d_out, int out_size, void* d_ws, size_t ws_size,
                              hipStream_t stream) {
  const float* x = (const float*)d_in[0];
  const float* w_wide = (const float*)d_in[1];
  const float* b_wide = (const float*)d_in[2];
  const float* V = (const float*)d_in[3];
  const float* w1 = (const float*)d_in[4];
  const float* b1 = (const float*)d_in[5];
  const float* w2 = (const float*)d_in[6];
  const float* b2 = (const float*)d_in[7];
  const float* w3 = (const float*)d_in[8];
  const float* b3 = (const float*)d_in[9];
  const float* w_out = (const float*)d_in[10];
  const float* b_out = (const float*)d_in[11];
  float* out = (float*)d_out;
  char* ws = (char*)d_ws;

  f16* VT_h = (f16*)(ws + OFF_VT_H);
  f16* VT_l = (f16*)(ws + OFF_VT_L);
  f16* V2T = (f16*)(ws + OFF_V2T);
  f16* W1T_h = (f16*)(ws + OFF_W1T_H);
  f16* W1T_l = (f16*)(ws + OFF_W1T_L);
  f16* W2T_h = (f16*)(ws + OFF_W2T_H);
  f16* W2T_l = (f16*)(ws + OFF_W2T_L);
  f16* W3T_h = (f16*)(ws + OFF_W3T_H);
  f16* W3T_l = (f16*)(ws + OFF_W3T_L);

  prep_kernel<<<256, 256, 0, stream>>>(V, w1, w2, w3, VT_h, VT_l, V2T, W1T_h,
                                       W1T_l, W2T_h, W2T_l, W3T_h, W3T_l);

  fused_kernel<<<NROWS / ROWS, 512, 0, stream>>>(
      x, w_wide, b_wide, VT_h, VT_l, V2T, W1T_h, W1T_l, b1, W2T_h, W2T_l, b2,
      W3T_h, W3T_l, b3, w_out, b_out, out);
}